// Round 1
// baseline (1677.953 us; speedup 1.0000x reference)
//
#include <hip/hip_runtime.h>
#include <hip/hip_bf16.h>
#include <stdint.h>

// Encoder: B=2,S=2048,D=1024,HID=1024,NH=16,C=64,L=4. 4096 token-rows.
#define TOK 4096
#define DM  1024

using u16 = unsigned short;
typedef __attribute__((ext_vector_type(8))) short short8;   // bf16x8 frag (4 VGPR)
typedef __attribute__((ext_vector_type(4))) float f32x4;

__device__ __forceinline__ u16 f2bf(float f){
  unsigned u = __float_as_uint(f);
  return (u16)((u + 0x7fffu + ((u >> 16) & 1u)) >> 16);   // RNE
}
__device__ __forceinline__ float bf2f(u16 h){ return __uint_as_float(((unsigned)h) << 16); }

// ---------------- pos-enc add: r = x + pe, xb = bf16(r) ----------------
__global__ __launch_bounds__(256) void posenc_add(
    const float* __restrict__ x, float* __restrict__ r, u16* __restrict__ xb)
{
  const int t = blockIdx.x;          // token row 0..4095
  const int s = t & 2047;            // seq position
  const size_t base = (size_t)t * DM;
#pragma unroll
  for (int i = 0; i < 4; ++i){
    const int d = threadIdx.x + i * 256;
    const float e = (float)(d & ~1) * (1.0f / (float)DM);
    const float denom = powf(1000.0f, e);
    const float mat = (float)s / denom;
    const float pe = (d & 1) ? cosf(mat) : sinf(mat);
    const float v = x[base + d] + pe;
    r[base + d] = v;
    xb[base + d] = f2bf(v);
  }
}

// ---------- per-layer weight transpose+cast: 6 matrices [1024][1024] f32 -> [N][K] bf16 ----------
// WT layout: [0]=WqT [1]=WkT [2]=WvT (contiguous 3072x1024 for fused qkv) [3]=WoT [4]=W1T [5]=W2T
__global__ __launch_bounds__(256) void transpose6(
    const float* __restrict__ Wq, const float* __restrict__ Wk, const float* __restrict__ Wv,
    const float* __restrict__ Wo, const float* __restrict__ W1, const float* __restrict__ W2,
    u16* __restrict__ WT, int l)
{
  __shared__ float tile[32][33];
  const int bid = blockIdx.x;
  const int m = bid >> 10;           // matrix 0..5
  const int t = bid & 1023;
  const int tn = (t & 31) * 32;
  const int tk = (t >> 5) * 32;
  const float* src = (m==0)?Wq:(m==1)?Wk:(m==2)?Wv:(m==3)?Wo:(m==4)?W1:W2;
  src += (size_t)l * 1048576;
  u16* dst = WT + (size_t)m * 1048576;
  const int tx = threadIdx.x & 31, ty = threadIdx.x >> 5;
#pragma unroll
  for (int i = 0; i < 4; ++i)
    tile[ty + i*8][tx] = src[(size_t)(tk + ty + i*8) * 1024 + tn + tx];
  __syncthreads();
#pragma unroll
  for (int i = 0; i < 4; ++i)
    dst[(size_t)(tn + ty + i*8) * 1024 + tk + tx] = f2bf(tile[tx][ty + i*8]);
}

// ---------------- bf16 MFMA GEMM: C[M][N] = A[M][1024] @ BT[N][1024]^T ----------------
// MODE 0: +bias -> f32 out ; MODE 1: relu(+bias) -> bf16 ; MODE 2: qkv (+bias triple, q*=0.125) -> bf16
#define BM 128
#define BN 128
#define BK 64
#define KD 1024

template<int MODE>
__global__ __launch_bounds__(256) void gemm_k1024(
    const u16* __restrict__ A, const u16* __restrict__ BT,
    const float* __restrict__ bias0, const float* __restrict__ bias1, const float* __restrict__ bias2,
    float* __restrict__ outF, u16* __restrict__ outB, int M, int N)
{
  __shared__ __align__(16) u16 sA[2][BM*BK];
  __shared__ __align__(16) u16 sB[2][BN*BK];
  const int tid  = threadIdx.x;
  const int lane = tid & 63;
  const int wave = tid >> 6;
  const int nbn = N / BN;
  const size_t m0 = (size_t)(blockIdx.x / nbn) * BM;
  const size_t n0 = (size_t)(blockIdx.x % nbn) * BN;

  // staging geometry: each thread owns 4 chunks of 16B per tile (A and B)
  const int r0 = tid >> 3;               // 0..31 (+p*32)
  const int c8 = tid & 7;                // 16B slot within 128B row
  const int slot = c8 ^ (r0 & 7);        // T2 XOR swizzle (rows stride 128B)
  const int ldsoff = r0 * 128 + slot * 16;

  uint4 ra[4], rb[4];
  auto load_tile = [&](int kt){
    const int k0 = kt * BK;
#pragma unroll
    for (int p = 0; p < 4; ++p){
      ra[p] = *(const uint4*)(A  + (m0 + p*32 + r0) * KD + k0 + c8*8);
      rb[p] = *(const uint4*)(BT + (n0 + p*32 + r0) * KD + k0 + c8*8);
    }
  };
  auto store_tile = [&](int buf){
#pragma unroll
    for (int p = 0; p < 4; ++p){
      *(uint4*)((char*)sA[buf] + p*4096 + ldsoff) = ra[p];
      *(uint4*)((char*)sB[buf] + p*4096 + ldsoff) = rb[p];
    }
  };

  const int wm = (wave >> 1) * 64;
  const int wn = (wave & 1) * 64;
  f32x4 acc[4][4] = {};

  load_tile(0);
  int cur = 0;
  for (int kt = 0; kt < KD/BK; ++kt){
    store_tile(cur);
    __syncthreads();
    if (kt + 1 < KD/BK) load_tile(kt + 1);   // overlap next-tile HBM loads with MFMA
#pragma unroll
    for (int kk = 0; kk < 2; ++kk){
      short8 af[4], bf[4];
      const int kidx = kk*4 + (lane >> 4);
      const int ksl  = (kidx ^ (lane & 7)) * 16;   // swizzled 16B slot (row&7 == lane&7)
#pragma unroll
      for (int i = 0; i < 4; ++i){
        const int arow = wm + i*16 + (lane & 15);
        af[i] = *(const short8*)((const char*)sA[cur] + arow*128 + ksl);
        const int brow = wn + i*16 + (lane & 15);
        bf[i] = *(const short8*)((const char*)sB[cur] + brow*128 + ksl);
      }
#pragma unroll
      for (int i = 0; i < 4; ++i)
#pragma unroll
        for (int j = 0; j < 4; ++j)
          acc[i][j] = __builtin_amdgcn_mfma_f32_16x16x32_bf16(af[i], bf[j], acc[i][j], 0, 0, 0);
    }
    __syncthreads();
    cur ^= 1;
  }

  // epilogue: C/D mapping col=lane&15, row=(lane>>4)*4+r  [verified m89]
#pragma unroll
  for (int i = 0; i < 4; ++i){
    const int growb = wm + i*16 + (lane >> 4) * 4;
#pragma unroll
    for (int j = 0; j < 4; ++j){
      const size_t gcol = n0 + wn + j*16 + (lane & 15);
      float bv;
      if constexpr (MODE == 2)
        bv = (gcol < 1024) ? bias0[gcol] : (gcol < 2048) ? bias1[gcol - 1024] : bias2[gcol - 2048];
      else
        bv = bias0[gcol];
#pragma unroll
      for (int r = 0; r < 4; ++r){
        const size_t grow = m0 + growb + r;
        float v = acc[i][j][r] + bv;
        if constexpr (MODE == 0)      outF[grow * N + gcol] = v;
        else if constexpr (MODE == 1) outB[grow * N + gcol] = f2bf(fmaxf(v, 0.0f));
        else                          outB[grow * N + gcol] = f2bf(gcol < 1024 ? v * 0.125f : v);
      }
    }
  }
}

// ---------------- per-token channel attention ----------------
// qkv[t][0:1024]=q(scaled) [1024:2048]=k [2048:3072]=v, per head 64 ch.
// One wave per (token, head); lane i = query channel i; softmax over j<=i.
__global__ __launch_bounds__(256) void attn_chan(
    const u16* __restrict__ qkv, u16* __restrict__ av)
{
  __shared__ float sq[256], sk[256], sv[256];
  const int t  = blockIdx.x >> 2;
  const int hb = blockIdx.x & 3;           // head-block: heads hb*4 .. hb*4+3
  const int tid = threadIdx.x;
  const size_t base = (size_t)t * 3072 + hb * 256;
  sq[tid] = bf2f(qkv[base + tid]);
  sk[tid] = bf2f(qkv[base + 1024 + tid]);
  sv[tid] = bf2f(qkv[base + 2048 + tid]);
  __syncthreads();
  const int wave = tid >> 6, i = tid & 63;
  const float qi = sq[wave*64 + i];
  const float* kw = sk + wave*64;
  const float* vw = sv + wave*64;
  float m = -3.0e38f;
  for (int j = 0; j <= i; ++j) m = fmaxf(m, qi * kw[j]);
  float ssum = 0.0f, acc = 0.0f;
  for (int j = 0; j <= i; ++j){
    const float e = __expf(qi * kw[j] - m);
    ssum += e; acc += e * vw[j];
  }
  av[(size_t)t * 1024 + (size_t)(hb*4 + wave)*64 + i] = f2bf(acc / ssum);
}

// ---------------- residual add + LayerNorm (row of 1024) ----------------
__global__ __launch_bounds__(256) void residual_ln(
    const float* __restrict__ y, const float* xres,
    const float* __restrict__ gamma, const float* __restrict__ beta,
    float* xout, u16* __restrict__ xb)
{
  __shared__ float red[4];
  const int row = blockIdx.x, tid = threadIdx.x;
  const int lane = tid & 63, wave = tid >> 6;
  const float4 a = ((const float4*)(y    + (size_t)row*DM))[tid];
  const float4 b = ((const float4*)(xres + (size_t)row*DM))[tid];
  float4 s; s.x=a.x+b.x; s.y=a.y+b.y; s.z=a.z+b.z; s.w=a.w+b.w;
  float p = s.x + s.y + s.z + s.w;
#pragma unroll
  for (int o = 32; o; o >>= 1) p += __shfl_xor(p, o);
  if (lane == 0) red[wave] = p;
  __syncthreads();
  const float mu = (red[0]+red[1]+red[2]+red[3]) * (1.0f/(float)DM);
  __syncthreads();
  const float dx=s.x-mu, dy=s.y-mu, dz=s.z-mu, dw=s.w-mu;
  float q2 = dx*dx + dy*dy + dz*dz + dw*dw;
#pragma unroll
  for (int o = 32; o; o >>= 1) q2 += __shfl_xor(q2, o);
  if (lane == 0) red[wave] = q2;
  __syncthreads();
  const float var = (red[0]+red[1]+red[2]+red[3]) * (1.0f/(float)DM);
  const float rstd = rsqrtf(var + 1e-5f);
  const float4 g  = ((const float4*)gamma)[tid];
  const float4 be = ((const float4*)beta)[tid];
  float4 o4;
  o4.x = dx*rstd*g.x + be.x;
  o4.y = dy*rstd*g.y + be.y;
  o4.z = dz*rstd*g.z + be.z;
  o4.w = dw*rstd*g.w + be.w;
  ((float4*)(xout + (size_t)row*DM))[tid] = o4;
  ushort4 ob; ob.x=f2bf(o4.x); ob.y=f2bf(o4.y); ob.z=f2bf(o4.z); ob.w=f2bf(o4.w);
  ((ushort4*)(xb + (size_t)row*DM))[tid] = ob;
}

// ---------------------------------------------------------------------------
extern "C" void kernel_launch(void* const* d_in, const int* in_sizes, int n_in,
                              void* d_out, int out_size, void* d_ws, size_t ws_size,
                              hipStream_t stream)
{
  const float* x    = (const float*)d_in[0];
  const float* Wq   = (const float*)d_in[1];
  const float* bq   = (const float*)d_in[2];
  const float* Wk   = (const float*)d_in[3];
  const float* bk   = (const float*)d_in[4];
  const float* Wv   = (const float*)d_in[5];
  const float* bv   = (const float*)d_in[6];
  const float* Wo   = (const float*)d_in[7];
  const float* bo   = (const float*)d_in[8];
  const float* W1   = (const float*)d_in[9];
  const float* b1   = (const float*)d_in[10];
  const float* W2   = (const float*)d_in[11];
  const float* b2   = (const float*)d_in[12];
  const float* gam  = (const float*)d_in[13];
  const float* bet  = (const float*)d_in[14];

  char* ws = (char*)d_ws;
  size_t off = 0;
  auto alloc = [&](size_t b){ void* p = ws + off; off = (off + b + 255) & ~(size_t)255; return p; };
  u16*   WT   = (u16*)  alloc(6ull*1048576*2);   // per-layer transposed bf16 weights (12.6 MB)
  float* res  = (float*)alloc((size_t)TOK*DM*4); // fp32 residual stream
  u16*   xb   = (u16*)  alloc((size_t)TOK*DM*2); // bf16 activations
  u16*   qkv  = (u16*)  alloc((size_t)TOK*3072*2);
  u16*   avb  = (u16*)  alloc((size_t)TOK*DM*2);
  u16*   hbuf = (u16*)  alloc((size_t)TOK*DM*2);
  float* ybuf = (float*)alloc((size_t)TOK*DM*4);
  if (off > ws_size) return;  // insufficient scratch -> fail loudly (poisoned d_out)

  posenc_add<<<TOK, 256, 0, stream>>>(x, res, xb);

  for (int l = 0; l < 4; ++l){
    transpose6<<<6*1024, 256, 0, stream>>>(Wq, Wk, Wv, Wo, W1, W2, WT, l);
    // q,k,v = x@W{q,k,v}+b (q pre-scaled by 1/8)
    gemm_k1024<2><<<(TOK/BM)*(3072/BN), 256, 0, stream>>>(
        xb, WT, bq + l*1024, bk + l*1024, bv + l*1024, nullptr, qkv, TOK, 3072);
    attn_chan<<<TOK*4, 256, 0, stream>>>(qkv, avb);
    // attn_out = av@Wo+bo -> f32
    gemm_k1024<0><<<(TOK/BM)*(1024/BN), 256, 0, stream>>>(
        avb, WT + 3ull*1048576, bo + l*1024, nullptr, nullptr, ybuf, nullptr, TOK, 1024);
    residual_ln<<<TOK, 256, 0, stream>>>(ybuf, res, gam + l*1024, bet + l*1024, res, xb);
    // h = relu(x@W1+b1) -> bf16
    gemm_k1024<1><<<(TOK/BM)*(1024/BN), 256, 0, stream>>>(
        xb, WT + 4ull*1048576, b1 + l*1024, nullptr, nullptr, nullptr, hbuf, TOK, 1024);
    // y = h@W2+b2 -> f32
    gemm_k1024<0><<<(TOK/BM)*(1024/BN), 256, 0, stream>>>(
        hbuf, WT + 5ull*1048576, b2 + l*1024, nullptr, nullptr, ybuf, nullptr, TOK, 1024);
    float* xdst = (l == 3) ? (float*)d_out : res;
    residual_ln<<<TOK, 256, 0, stream>>>(ybuf, res, gam + l*1024, bet + l*1024, xdst, xb);
  }
}

// Round 2
// 778.318 us; speedup vs baseline: 2.1559x; 2.1559x over previous
//
#include <hip/hip_runtime.h>
#include <hip/hip_bf16.h>
#include <stdint.h>

// Encoder: B=2,S=2048,D=1024,HID=1024,NH=16,C=64,L=4. 4096 token-rows.
#define TOK 4096
#define DM  1024

using u16 = unsigned short;
typedef __attribute__((ext_vector_type(8))) short short8;   // bf16x8 frag (4 VGPR)
typedef __attribute__((ext_vector_type(4))) float f32x4;

__device__ __forceinline__ u16 f2bf(float f){
  unsigned u = __float_as_uint(f);
  return (u16)((u + 0x7fffu + ((u >> 16) & 1u)) >> 16);   // RNE
}
__device__ __forceinline__ float bf2f(u16 h){ return __uint_as_float(((unsigned)h) << 16); }

// ---------------- pos-enc add: r = x + pe, xb = bf16(r) ----------------
__global__ __launch_bounds__(256) void posenc_add(
    const float* __restrict__ x, float* __restrict__ r, u16* __restrict__ xb)
{
  const int t = blockIdx.x;          // token row 0..4095
  const int s = t & 2047;            // seq position
  const size_t base = (size_t)t * DM;
#pragma unroll
  for (int i = 0; i < 4; ++i){
    const int d = threadIdx.x + i * 256;
    const float e = (float)(d & ~1) * (1.0f / (float)DM);
    const float denom = powf(1000.0f, e);
    const float mat = (float)s / denom;
    const float pe = (d & 1) ? cosf(mat) : sinf(mat);
    const float v = x[base + d] + pe;
    r[base + d] = v;
    xb[base + d] = f2bf(v);
  }
}

// ---------- per-layer weight transpose+cast: 6 matrices [1024][1024] f32 -> [N][K] bf16 ----------
// WT layout: [0]=WqT [1]=WkT [2]=WvT (contiguous 3072x1024 for fused qkv) [3]=WoT [4]=W1T [5]=W2T
__global__ __launch_bounds__(256) void transpose6(
    const float* __restrict__ Wq, const float* __restrict__ Wk, const float* __restrict__ Wv,
    const float* __restrict__ Wo, const float* __restrict__ W1, const float* __restrict__ W2,
    u16* __restrict__ WT, int l)
{
  __shared__ float tile[32][33];
  const int bid = blockIdx.x;
  const int m = bid >> 10;           // matrix 0..5
  const int t = bid & 1023;
  const int tn = (t & 31) * 32;
  const int tk = (t >> 5) * 32;
  const float* src = (m==0)?Wq:(m==1)?Wk:(m==2)?Wv:(m==3)?Wo:(m==4)?W1:W2;
  src += (size_t)l * 1048576;
  u16* dst = WT + (size_t)m * 1048576;
  const int tx = threadIdx.x & 31, ty = threadIdx.x >> 5;
#pragma unroll
  for (int i = 0; i < 4; ++i)
    tile[ty + i*8][tx] = src[(size_t)(tk + ty + i*8) * 1024 + tn + tx];
  __syncthreads();
#pragma unroll
  for (int i = 0; i < 4; ++i)
    dst[(size_t)(tn + ty + i*8) * 1024 + tk + tx] = f2bf(tile[tx][ty + i*8]);
}

// ---------------- bf16 MFMA GEMM: C[M][N] = A[M][1024] @ BT[N][1024]^T ----------------
// m97 structure: 128x128 tile, BK=64, single 32KB LDS buffer, global_load_lds(16B)
// staging with PRE-SWIZZLED global source + swizzled ds_read (both-sides swizzle).
// MODE 0: +bias -> f32 out ; MODE 1: relu(+bias) -> bf16 ; MODE 2: qkv (+bias triple, q*=0.125) -> bf16
#define BM 128
#define BN 128
#define BK 64
#define KD 1024

template<int MODE>
__global__ __launch_bounds__(256) void gemm_k1024(
    const u16* __restrict__ A, const u16* __restrict__ BT,
    const float* __restrict__ bias0, const float* __restrict__ bias1, const float* __restrict__ bias2,
    float* __restrict__ outF, u16* __restrict__ outB, int M, int N)
{
  __shared__ __align__(16) u16 sA[BM*BK];   // linear rows of 128B; CONTENT swizzled
  __shared__ __align__(16) u16 sB[BN*BK];
  const int tid  = threadIdx.x;
  const int lane = tid & 63;
  const int wave = tid >> 6;
  const int nbn = N / BN;
  const size_t m0 = (size_t)(blockIdx.x / nbn) * BM;
  const size_t n0 = (size_t)(blockIdx.x % nbn) * BN;

  // staging geometry: wave w owns rows [w*32, w*32+32), 4 chunks of 8 rows.
  // global_load_lds writes lane l at ldsbase + l*16B -> row=l>>3, slot=l&7.
  // LDS content at (row,slot16) must be A[m0+row][k0 + (slot^(row&7))*8],
  // so the SOURCE slot is pre-swizzled per lane.
  const int srow  = lane >> 3;               // 0..7 (row within chunk; row&7 == srow)
  const int sslot = (lane & 7) ^ srow;       // pre-swizzled 16B slot within 128B row
  const u16* gA = A  + (m0 + wave*32 + srow) * KD + sslot * 8;
  const u16* gB = BT + (n0 + wave*32 + srow) * KD + sslot * 8;
  u16* lA = sA + (wave*32) * 64;             // 64 u16 per row
  u16* lB = sB + (wave*32) * 64;

  const int wm = (wave >> 1) * 64;
  const int wn = (wave & 1) * 64;
  f32x4 acc[4][4] = {};

  for (int kt = 0; kt < KD/BK; ++kt){
    const int k0 = kt * BK;
#pragma unroll
    for (int p = 0; p < 4; ++p){
      __builtin_amdgcn_global_load_lds(
          (const __attribute__((address_space(1))) void*)(gA + p*8*KD + k0),
          (__attribute__((address_space(3))) void*)(lA + p*8*64), 16, 0, 0);
      __builtin_amdgcn_global_load_lds(
          (const __attribute__((address_space(1))) void*)(gB + p*8*KD + k0),
          (__attribute__((address_space(3))) void*)(lB + p*8*64), 16, 0, 0);
    }
    __syncthreads();   // compiler drains vmcnt(0) before barrier
#pragma unroll
    for (int kk = 0; kk < 2; ++kk){
      short8 af[4], bfr[4];
      const int kidx = kk*4 + (lane >> 4);   // 16B k-chunk 0..7
#pragma unroll
      for (int i = 0; i < 4; ++i){
        const int arow = wm + i*16 + (lane & 15);
        af[i]  = *(const short8*)(sA + arow*64 + (kidx ^ (arow & 7)) * 8);
        const int brow = wn + i*16 + (lane & 15);
        bfr[i] = *(const short8*)(sB + brow*64 + (kidx ^ (brow & 7)) * 8);
      }
#pragma unroll
      for (int i = 0; i < 4; ++i)
#pragma unroll
        for (int j = 0; j < 4; ++j)
          acc[i][j] = __builtin_amdgcn_mfma_f32_16x16x32_bf16(af[i], bfr[j], acc[i][j], 0, 0, 0);
    }
    __syncthreads();
  }

  // epilogue: C/D mapping col=lane&15, row=(lane>>4)*4+r  [verified m89]
#pragma unroll
  for (int i = 0; i < 4; ++i){
    const int growb = wm + i*16 + (lane >> 4) * 4;
#pragma unroll
    for (int j = 0; j < 4; ++j){
      const size_t gcol = n0 + wn + j*16 + (lane & 15);
      float bv;
      if constexpr (MODE == 2)
        bv = (gcol < 1024) ? bias0[gcol] : (gcol < 2048) ? bias1[gcol - 1024] : bias2[gcol - 2048];
      else
        bv = bias0[gcol];
#pragma unroll
      for (int r = 0; r < 4; ++r){
        const size_t grow = m0 + growb + r;
        float v = acc[i][j][r] + bv;
        if constexpr (MODE == 0)      outF[grow * N + gcol] = v;
        else if constexpr (MODE == 1) outB[grow * N + gcol] = f2bf(fmaxf(v, 0.0f));
        else                          outB[grow * N + gcol] = f2bf(gcol < 1024 ? v * 0.125f : v);
      }
    }
  }
}

// ---------------- per-token channel attention (wave-parallel) ----------------
// qkv[t][0:1024]=q(scaled) [1024:2048]=k [2048:3072]=v, per head 64 ch.
// One wave per (token, head); lane i = query channel i.
// Row max via prefix scan: m_i = max_{j<=i} q_i*k_j = q_i>=0 ? q_i*cummax(k) : q_i*cummin(k).
// Then ONE masked loop over all 64 j (no divergent ragged loops).
__global__ __launch_bounds__(256) void attn_chan(
    const u16* __restrict__ qkv, u16* __restrict__ av)
{
  __shared__ float2 skv[256];
  const int t  = blockIdx.x >> 2;
  const int hb = blockIdx.x & 3;           // head-block: heads hb*4 .. hb*4+3
  const int tid = threadIdx.x;
  const int i = tid & 63;
  const int wave = tid >> 6;
  const size_t base = (size_t)t * 3072 + hb * 256 + tid;
  const float qi = bf2f(qkv[base]);
  const float ki = bf2f(qkv[base + 1024]);
  const float vi = bf2f(qkv[base + 2048]);
  skv[tid] = make_float2(ki, vi);
  // inclusive prefix cummax/cummin of k over lanes
  float kmx = ki, kmn = ki;
#pragma unroll
  for (int o = 1; o < 64; o <<= 1){
    const float a = __shfl_up(kmx, o);
    const float b = __shfl_up(kmn, o);
    if (i >= o){ kmx = fmaxf(kmx, a); kmn = fminf(kmn, b); }
  }
  const float m = fmaxf(qi * kmx, qi * kmn);   // exact row max over j<=i
  __syncthreads();
  const float2* kw = skv + wave * 64;          // broadcast reads (same addr all lanes)
  float ssum = 0.0f, acc = 0.0f;
#pragma unroll 8
  for (int j = 0; j < 64; ++j){
    const float2 kv = kw[j];
    float a = qi * kv.x - m;
    a = (j <= i) ? a : -1e30f;                 // causal mask -> exp = 0
    const float e = __expf(a);
    ssum += e;
    acc  += e * kv.y;
  }
  av[(size_t)t * 1024 + hb * 256 + tid] = f2bf(acc / ssum);
}

// ---------------- residual add + LayerNorm (row of 1024) ----------------
__global__ __launch_bounds__(256) void residual_ln(
    const float* __restrict__ y, const float* xres,
    const float* __restrict__ gamma, const float* __restrict__ beta,
    float* xout, u16* __restrict__ xb)
{
  __shared__ float red[4];
  const int row = blockIdx.x, tid = threadIdx.x;
  const int lane = tid & 63, wave = tid >> 6;
  const float4 a = ((const float4*)(y    + (size_t)row*DM))[tid];
  const float4 b = ((const float4*)(xres + (size_t)row*DM))[tid];
  float4 s; s.x=a.x+b.x; s.y=a.y+b.y; s.z=a.z+b.z; s.w=a.w+b.w;
  float p = s.x + s.y + s.z + s.w;
#pragma unroll
  for (int o = 32; o; o >>= 1) p += __shfl_xor(p, o);
  if (lane == 0) red[wave] = p;
  __syncthreads();
  const float mu = (red[0]+red[1]+red[2]+red[3]) * (1.0f/(float)DM);
  __syncthreads();
  const float dx=s.x-mu, dy=s.y-mu, dz=s.z-mu, dw=s.w-mu;
  float q2 = dx*dx + dy*dy + dz*dz + dw*dw;
#pragma unroll
  for (int o = 32; o; o >>= 1) q2 += __shfl_xor(q2, o);
  if (lane == 0) red[wave] = q2;
  __syncthreads();
  const float var = (red[0]+red[1]+red[2]+red[3]) * (1.0f/(float)DM);
  const float rstd = rsqrtf(var + 1e-5f);
  const float4 g  = ((const float4*)gamma)[tid];
  const float4 be = ((const float4*)beta)[tid];
  float4 o4;
  o4.x = dx*rstd*g.x + be.x;
  o4.y = dy*rstd*g.y + be.y;
  o4.z = dz*rstd*g.z + be.z;
  o4.w = dw*rstd*g.w + be.w;
  ((float4*)(xout + (size_t)row*DM))[tid] = o4;
  ushort4 ob; ob.x=f2bf(o4.x); ob.y=f2bf(o4.y); ob.z=f2bf(o4.z); ob.w=f2bf(o4.w);
  ((ushort4*)(xb + (size_t)row*DM))[tid] = ob;
}

// ---------------------------------------------------------------------------
extern "C" void kernel_launch(void* const* d_in, const int* in_sizes, int n_in,
                              void* d_out, int out_size, void* d_ws, size_t ws_size,
                              hipStream_t stream)
{
  const float* x    = (const float*)d_in[0];
  const float* Wq   = (const float*)d_in[1];
  const float* bq   = (const float*)d_in[2];
  const float* Wk   = (const float*)d_in[3];
  const float* bk   = (const float*)d_in[4];
  const float* Wv   = (const float*)d_in[5];
  const float* bv   = (const float*)d_in[6];
  const float* Wo   = (const float*)d_in[7];
  const float* bo   = (const float*)d_in[8];
  const float* W1   = (const float*)d_in[9];
  const float* b1   = (const float*)d_in[10];
  const float* W2   = (const float*)d_in[11];
  const float* b2   = (const float*)d_in[12];
  const float* gam  = (const float*)d_in[13];
  const float* bet  = (const float*)d_in[14];

  char* ws = (char*)d_ws;
  size_t off = 0;
  auto alloc = [&](size_t b){ void* p = ws + off; off = (off + b + 255) & ~(size_t)255; return p; };
  u16*   WT   = (u16*)  alloc(6ull*1048576*2);   // per-layer transposed bf16 weights (12.6 MB)
  float* res  = (float*)alloc((size_t)TOK*DM*4); // fp32 residual stream
  u16*   xb   = (u16*)  alloc((size_t)TOK*DM*2); // bf16 activations
  u16*   qkv  = (u16*)  alloc((size_t)TOK*3072*2);
  u16*   avb  = (u16*)  alloc((size_t)TOK*DM*2);
  u16*   hbuf = (u16*)  alloc((size_t)TOK*DM*2);
  float* ybuf = (float*)alloc((size_t)TOK*DM*4);
  if (off > ws_size) return;  // insufficient scratch -> fail loudly (poisoned d_out)

  posenc_add<<<TOK, 256, 0, stream>>>(x, res, xb);

  for (int l = 0; l < 4; ++l){
    transpose6<<<6*1024, 256, 0, stream>>>(Wq, Wk, Wv, Wo, W1, W2, WT, l);
    // q,k,v = x@W{q,k,v}+b (q pre-scaled by 1/8)
    gemm_k1024<2><<<(TOK/BM)*(3072/BN), 256, 0, stream>>>(
        xb, WT, bq + l*1024, bk + l*1024, bv + l*1024, nullptr, qkv, TOK, 3072);
    attn_chan<<<TOK*4, 256, 0, stream>>>(qkv, avb);
    // attn_out = av@Wo+bo -> f32
    gemm_k1024<0><<<(TOK/BM)*(1024/BN), 256, 0, stream>>>(
        avb, WT + 3ull*1048576, bo + l*1024, nullptr, nullptr, ybuf, nullptr, TOK, 1024);
    residual_ln<<<TOK, 256, 0, stream>>>(ybuf, res, gam + l*1024, bet + l*1024, res, xb);
    // h = relu(x@W1+b1) -> bf16
    gemm_k1024<1><<<(TOK/BM)*(1024/BN), 256, 0, stream>>>(
        xb, WT + 4ull*1048576, b1 + l*1024, nullptr, nullptr, nullptr, hbuf, TOK, 1024);
    // y = h@W2+b2 -> f32
    gemm_k1024<0><<<(TOK/BM)*(1024/BN), 256, 0, stream>>>(
        hbuf, WT + 5ull*1048576, b2 + l*1024, nullptr, nullptr, ybuf, nullptr, TOK, 1024);
    float* xdst = (l == 3) ? (float*)d_out : res;
    residual_ln<<<TOK, 256, 0, stream>>>(ybuf, res, gam + l*1024, bet + l*1024, xdst, xb);
  }
}